// Round 9
// baseline (411.522 us; speedup 1.0000x reference)
//
#include <hip/hip_runtime.h>
#include <stdint.h>

// ---------------- types / helpers ----------------
typedef short short8 __attribute__((ext_vector_type(8)));
typedef float f32x4 __attribute__((ext_vector_type(4)));

__device__ __forceinline__ unsigned short f2bf(float f) {
  union { float f; unsigned u; } v; v.f = f;
  unsigned u = v.u;
  u += 0x7fffu + ((u >> 16) & 1u);   // RNE
  return (unsigned short)(u >> 16);
}

__device__ __forceinline__ void gl16(const void* g, void* l) {
  __builtin_amdgcn_global_load_lds(
      (__attribute__((address_space(1))) void*)(uintptr_t)g,
      (__attribute__((address_space(3))) void*)l, 16, 0, 0);
}

// Problem constants
#define NSPAT 36992
#define PLANE 4624        // 68*68
#define XHP_ROWS 37152    // NSPAT + margin rows

// ---------------- kernel 1: styles ----------------
__global__ void styles_kernel(const float* __restrict__ w_lat, const float* __restrict__ affw,
                              const float* __restrict__ affb, float* __restrict__ s) {
  int g = blockIdx.x * 256 + threadIdx.x;   // 0..4095
  int b = g >> 9, i = g & 511;
  const float4* wl = (const float4*)(w_lat + b * 512);
  const float4* aw = (const float4*)(affw + (size_t)i * 512);
  float acc = 0.f;
#pragma unroll 4
  for (int j = 0; j < 128; ++j) {
    float4 a = wl[j], c = aw[j];
    acc += a.x * c.x + a.y * c.y + a.z * c.z + a.w * c.w;
  }
  s[g] = acc * 0.044194173824159216f + affb[i];
}

// ---------------- kernel 2: global normalize s ----------------
__global__ void norm_kernel(float* __restrict__ s, float* __restrict__ s2) {
  __shared__ float red[256];
  int t = threadIdx.x;
  float acc = 0.f;
  for (int e = t; e < 4096; e += 256) { float v = s[e]; acc += v * v; }
  red[t] = acc; __syncthreads();
  for (int st = 128; st > 0; st >>= 1) {
    if (t < st) red[t] += red[t + st];
    __syncthreads();
  }
  float alpha = rsqrtf(red[0] * (1.0f / 4096.0f));
  for (int e = t; e < 4096; e += 256) {
    float v = s[e] * alpha;
    s[e] = v; s2[e] = v * v;
  }
}

// ---------------- kernel 3: per-output-channel weight scale ----------------
__global__ void rowscale_kernel(const float* __restrict__ convw, float* __restrict__ rowscale) {
  int o = blockIdx.x, t = threadIdx.x;
  const float* wr = convw + (size_t)o * 4608;
  float acc = 0.f;
  for (int e = t; e < 4608; e += 256) { float v = wr[e]; acc += v * v; }
  __shared__ float red[256];
  red[t] = acc; __syncthreads();
  for (int st = 128; st > 0; st >>= 1) {
    if (t < st) red[t] += red[t + st];
    __syncthreads();
  }
  if (t == 0) rowscale[o] = rsqrtf(red[0] * (1.0f / 4608.0f));
}

// ---------------- kernel 4: bf16 weights (tap, o, i) + W2 ----------------
__global__ void wprep_kernel(const float* __restrict__ convw, const float* __restrict__ rowscale,
                             unsigned short* __restrict__ wbf, float* __restrict__ W2) {
  int o = blockIdx.x, t = threadIdx.x;
  float sc = rowscale[o];
  for (int i = t; i < 512; i += 256) {
    const float* wp = convw + ((size_t)o * 512 + i) * 9;
    float w9[9]; float ss = 0.f;
#pragma unroll
    for (int m = 0; m < 9; ++m) { float v = wp[m] * sc; w9[m] = v; ss += v * v; }
    W2[((size_t)o << 9) + i] = ss;
#pragma unroll
    for (int m = 0; m < 9; ++m)
      wbf[(((size_t)m * 512 + o) << 9) + i] = f2bf(w9[m]);
  }
}

// ---------------- kernel 5: demod ----------------
__global__ void demod_kernel(const float* __restrict__ s2, const float* __restrict__ W2,
                             float* __restrict__ dbuf) {
  int g = blockIdx.x * 256 + threadIdx.x;
  int b = g >> 9, o = g & 511;
  const float4* sp = (const float4*)(s2 + b * 512);
  const float4* wp = (const float4*)(W2 + (size_t)o * 512);
  float acc = 1e-8f;
#pragma unroll 4
  for (int j = 0; j < 128; ++j) {
    float4 a = sp[j], c = wp[j];
    acc += a.x * c.x + a.y * c.y + a.z * c.z + a.w * c.w;
  }
  dbuf[g] = rsqrtf(acc);
}

// ---------------- kernel 6: x-hat NHWC padded bf16 ----------------
__global__ void xprep_kernel(const float* __restrict__ x, const float* __restrict__ s,
                             unsigned short* __restrict__ xhp) {
  int b = blockIdx.x >> 6, h = blockIdx.x & 63;
  int t = threadIdx.x;
  __shared__ float tile[64 * 65];
  __shared__ float sv[64];
  for (int it = 0; it < 8; ++it) {
    int i0 = it * 64;
    {
      int ii = t >> 2, wseg = (t & 3) * 16;
      const float4* src = (const float4*)(x + (((size_t)(b * 512 + i0 + ii) * 64 + h) << 6) + wseg);
      float4 v0 = src[0], v1 = src[1], v2 = src[2], v3 = src[3];
      float* dst = tile + ii * 65 + wseg;
      dst[0]=v0.x; dst[1]=v0.y; dst[2]=v0.z; dst[3]=v0.w;
      dst[4]=v1.x; dst[5]=v1.y; dst[6]=v1.z; dst[7]=v1.w;
      dst[8]=v2.x; dst[9]=v2.y; dst[10]=v2.z; dst[11]=v2.w;
      dst[12]=v3.x; dst[13]=v3.y; dst[14]=v3.z; dst[15]=v3.w;
    }
    if (t < 64) sv[t] = s[b * 512 + i0 + t];
    __syncthreads();
    {
      int w = t >> 2, ic = (t & 3) * 16;
      alignas(16) unsigned short tmp[16];
#pragma unroll
      for (int k = 0; k < 16; ++k)
        tmp[k] = f2bf(tile[(ic + k) * 65 + w] * sv[ic + k]);
      unsigned short* dst = xhp + ((size_t)b * PLANE + (h + 2) * 68 + (w + 2)) * 512 + i0 + ic;
      *(short8*)dst = *(const short8*)tmp;
      *(short8*)(dst + 8) = *(const short8*)(tmp + 8);
    }
    __syncthreads();
  }
}

// ---------------- kernel 7: implicit-GEMM conv, 256o x 128n block, wave = 128m x 64n ----------------
// Fat wave tile (12 ds_read_b128 / 32 MFMA per K-step -> compute-bound ratio) +
// n-major XCD chunking (B slice stays in this XCD's L2 across both o-tiles; R3-proven low FETCH) +
// 3-deep counted-vmcnt pipeline + sigma LDS swizzle (0 conflicts, R3/R4-proven).
__global__ __launch_bounds__(256, 2) void conv_kernel(const unsigned short* __restrict__ wbf,
                                                      const unsigned short* __restrict__ xhp,
                                                      const float* __restrict__ dbuf,
                                                      const float* __restrict__ convb,
                                                      float* __restrict__ ybuf) {
  extern __shared__ unsigned short lds[];  // 3 bufs x (A 8192 + B 4096) shorts = 72 KB
  const int t = threadIdx.x;
  const int lane = t & 63, wid = t >> 6;

  // n-major flat id: orig = ntile*2 + otile ; bijective XCD chunking nwg=578, q=72, r=2
  int orig = blockIdx.y * 2 + blockIdx.x;
  int xcd = orig & 7, idx = orig >> 3;
  int wg = (xcd < 2) ? (xcd * 73 + idx) : (146 + (xcd - 2) * 72 + idx);
  const int n0 = (wg >> 1) * 128, o0 = (wg & 1) * 256;
  const int wm = wid >> 1, wn = wid & 1;

  // staging: lane l stages global quarter q=(l&3)^((l>>3)&3) of row (base + (l>>2))
  const unsigned kc = (((unsigned)(lane & 3)) ^ ((unsigned)(lane >> 3) & 3u)) * 8u;
  const unsigned aOff0 = (unsigned)(o0 + wid * 64 + (lane >> 2)) * 512 + kc;  // +c*8192, c<4
  const unsigned bOff0 = (unsigned)(n0 + wid * 32 + (lane >> 2)) * 512 + kc;  // +c*8192, c<2

  // frag read: row r=lane&15, phys quarter = (lane>>4) ^ ((r>>1)&3)
  const unsigned xq = ((unsigned)(lane >> 4)) ^ (((unsigned)(lane & 15) >> 1) & 3u);
  const unsigned aFo = (unsigned)(wm * 128 + (lane & 15)) * 32 + xq * 8;          // + mi*512
  const unsigned bFo = 8192u + (unsigned)(wn * 64 + (lane & 15)) * 32 + xq * 8;   // + ni*512

  f32x4 acc[8][4] = {};

#define STAGE(stp, off) do {                                           \
    const unsigned tp = (unsigned)(stp) >> 4;                          \
    const unsigned k0 = ((unsigned)(stp) & 15u) * 32u;                 \
    const unsigned aT = tp * 262144u + k0;                             \
    const unsigned bS = ((tp / 3u) * 68u + (tp % 3u)) * 512u + k0;     \
    unsigned short* la = lds + (off) + wid * 2048;                     \
    unsigned short* lb = lds + (off) + 8192 + wid * 1024;              \
    gl16(wbf + aT + aOff0,          la);                               \
    gl16(wbf + aT + aOff0 + 8192,   la + 512);                         \
    gl16(wbf + aT + aOff0 + 16384,  la + 1024);                        \
    gl16(wbf + aT + aOff0 + 24576,  la + 1536);                        \
    gl16(xhp + bS + bOff0,          lb);                               \
    gl16(xhp + bS + bOff0 + 8192,   lb + 512);                         \
  } while (0)

#define COMPUTE(rdoff) do {                                            \
    const unsigned short* aF = lds + (rdoff) + aFo;                    \
    const unsigned short* bF = lds + (rdoff) + bFo;                    \
    short8 bfr[4];                                                     \
    _Pragma("unroll")                                                  \
    for (int ni = 0; ni < 4; ++ni) bfr[ni] = *(const short8*)(bF + ni * 512); \
    __builtin_amdgcn_s_setprio(1);                                     \
    _Pragma("unroll")                                                  \
    for (int mi = 0; mi < 8; ++mi) {                                   \
      short8 afr = *(const short8*)(aF + mi * 512);                    \
      _Pragma("unroll")                                                \
      for (int ni = 0; ni < 4; ++ni)                                   \
        acc[mi][ni] = __builtin_amdgcn_mfma_f32_16x16x32_bf16(afr, bfr[ni], acc[mi][ni], 0, 0, 0); \
    }                                                                  \
    __builtin_amdgcn_s_setprio(0);                                     \
  } while (0)

  STAGE(0, 0u);
  STAGE(1, 12288u);

  unsigned rd = 0, wr2 = 24576;
  for (int step = 0; step < 143; ++step) {
    asm volatile("s_waitcnt vmcnt(6)" ::: "memory");   // oldest stage's 6 loads landed
    __builtin_amdgcn_s_barrier();
    asm volatile("" ::: "memory");
    if (step < 142) STAGE(step + 2, wr2);
    COMPUTE(rd);
    asm volatile("" ::: "memory");
    rd += 12288;  if (rd == 36864) rd = 0;
    wr2 += 12288; if (wr2 == 36864) wr2 = 0;
  }
  asm volatile("s_waitcnt vmcnt(0)" ::: "memory");
  __builtin_amdgcn_s_barrier();
  asm volatile("" ::: "memory");
  COMPUTE(rd);
#undef STAGE
#undef COMPUTE

  // epilogue
  const int col = lane & 15;
  const int rbase = (lane >> 4) * 4;
#pragma unroll
  for (int ni = 0; ni < 4; ++ni) {
    const unsigned n = (unsigned)(n0 + wn * 64 + ni * 16 + col);
    const unsigned b = n / 4624u;
    const float* dr = dbuf + b * 512;
#pragma unroll
    for (int mi = 0; mi < 8; ++mi) {
      const int ob = o0 + wm * 128 + mi * 16 + rbase;
#pragma unroll
      for (int j = 0; j < 4; ++j) {
        const int o = ob + j;
        float v = acc[mi][ni][j] * dr[o] + convb[o];
        v = fminf(fmaxf(v, -256.f), 256.f);
        ybuf[(size_t)o * NSPAT + n] = v;
      }
    }
  }
}

// ---------------- kernel 8: fused up2 + lrelu + down2, z kept in registers ----------------
// Down filters commute (separable): do v-up + lrelu + v-down fused per column, then h-down.
// 2 blocks per channel (output col halves). LDS: uhB[66][76] | uB[66][44] / dvT[64][76] overlay.
// Peak 9880 floats = 39.5 KB -> 4 blocks/CU.
__global__ __launch_bounds__(256, 4) void updown_kernel(const float* __restrict__ ybuf,
                                                        const float* __restrict__ upf,
                                                        const float* __restrict__ dnf,
                                                        float* __restrict__ out) {
  __shared__ float sm[9880];
  float* uhB = sm;            // [66][76]
  float* uB  = sm + 5016;     // [66][44]
  float* dvT = sm + 5016;     // [64][76] overlay (uB dead after P2)

  const int blk = blockIdx.x;
  const int half = blk & 1, ch = blk >> 1;
  const int o = ch & 511, b = ch >> 9;
  const float* ybase = ybuf + (size_t)o * NSPAT + b * PLANE;
  const int t = threadIdx.x;
  const int uc0 = half * 32 - 4;   // u window global col start (width 44)

  float f2[12], g[12];
#pragma unroll
  for (int m = 0; m < 12; ++m) { f2[m] = upf[11 - m] * 2.0f; g[m] = dnf[11 - m]; }

  // P1: load u window [66][44] via f32x4, zero-masked outside valid cols [0,66)
  for (int u = t; u < 726; u += 256) {
    int p = u / 11, q = u - p * 11;
    int gc = uc0 + 4 * q;
    f32x4 v = {0.f, 0.f, 0.f, 0.f};
    if (gc >= 0 && gc < 66) {
      v = *(const f32x4*)(ybase + p * 68 + gc);
#pragma unroll
      for (int j = 0; j < 4; ++j)
        if (gc + j >= 66) v[j] = 0.f;
    }
    *(f32x4*)(uB + p * 44 + 4 * q) = v;
  }
  __syncthreads();

  // P2: horizontal upsample. units (p<66, cq<19): uh local cols 4cq..4cq+3
  for (int u = t; u < 1254; u += 256) {
    int p = u / 19, cq = u - p * 19;
    const float* ur = uB + p * 44 + 2 * cq;
    float R0 = ur[0], R1 = ur[1], R2 = ur[2], R3 = ur[3], R4 = ur[4], R5 = ur[5], R6 = ur[6];
    f32x4 o4;
    o4[0] = f2[1]*R0 + f2[3]*R1 + f2[5]*R2 + f2[7]*R3 + f2[9]*R4 + f2[11]*R5;
    o4[1] = f2[0]*R0 + f2[2]*R1 + f2[4]*R2 + f2[6]*R3 + f2[8]*R4 + f2[10]*R5;
    o4[2] = f2[1]*R1 + f2[3]*R2 + f2[5]*R3 + f2[7]*R4 + f2[9]*R5 + f2[11]*R6;
    o4[3] = f2[0]*R1 + f2[2]*R2 + f2[4]*R3 + f2[6]*R4 + f2[8]*R5 + f2[10]*R6;
    *(f32x4*)(uhB + p * 76 + 4 * cq) = o4;
  }
  __syncthreads();

  // P3': fused vertical up + lrelu + vertical down, per column, z in registers.
  // units (cl<75, sg<3): s range [22sg, 22sg+21] clipped to <64
  if (t < 225) {
    const int cl = t % 75, sg = t / 75;
    const int s0 = sg * 22;
    const int ttg0 = 2 * s0;
    float R[32];
#pragma unroll
    for (int k = 0; k < 32; ++k) {
      int j = s0 - 4 + k;
      R[k] = (j >= 0 && j < 66) ? uhB[j * 76 + cl] : 0.f;
    }
    float dv[22];
#pragma unroll
    for (int m = 0; m < 22; ++m) dv[m] = 0.f;
#pragma unroll
    for (int k = 0; k < 54; ++k) {
      const int kb = k >> 1;
      float z;
      if (k & 1)
        z = f2[0]*R[kb] + f2[2]*R[kb+1] + f2[4]*R[kb+2] + f2[6]*R[kb+3] + f2[8]*R[kb+4] + f2[10]*R[kb+5];
      else
        z = f2[1]*R[kb] + f2[3]*R[kb+1] + f2[5]*R[kb+2] + f2[7]*R[kb+3] + f2[9]*R[kb+4] + f2[11]*R[kb+5];
      z = (z > 0.f ? z : 0.2f * z) * 1.4142135623730951f;
      z = fminf(fmaxf(z, -256.f), 256.f);
      if (ttg0 + k >= 138) z = 0.f;   // rows beyond z extent (only feeds unwritten dv)
      const int mlo = (k < 11) ? 0 : ((k - 10) >> 1);
      const int mhi = ((k >> 1) < 21) ? (k >> 1) : 21;
#pragma unroll
      for (int m = mlo; m <= mhi; ++m)
        dv[m] += g[k - 2 * m] * z;
    }
#pragma unroll
    for (int m = 0; m < 22; ++m) {
      const int s = s0 + m;
      if (s < 64) dvT[s * 76 + cl] = dv[m];
    }
  }
  __syncthreads();

  // P4': horizontal downsample + store. units (s<64, rq<4): out cols 32h+8rq..+7, exactly 256
  {
    const int s = t >> 2, rq = t & 3;
    const float* dr = dvT + s * 76 + 16 * rq;
    f32x4 dd[7];
#pragma unroll
    for (int i = 0; i < 7; ++i) dd[i] = *(const f32x4*)(dr + 4 * i);
    float D[28];
#pragma unroll
    for (int i = 0; i < 7; ++i) {
      D[4*i+0] = dd[i][0]; D[4*i+1] = dd[i][1]; D[4*i+2] = dd[i][2]; D[4*i+3] = dd[i][3];
    }
    f32x4 o0, o1;
#pragma unroll
    for (int m = 0; m < 8; ++m) {
      float v = g[0]*D[2*m] + g[1]*D[2*m+1] + g[2]*D[2*m+2] + g[3]*D[2*m+3]
              + g[4]*D[2*m+4] + g[5]*D[2*m+5] + g[6]*D[2*m+6] + g[7]*D[2*m+7]
              + g[8]*D[2*m+8] + g[9]*D[2*m+9] + g[10]*D[2*m+10] + g[11]*D[2*m+11];
      if (m < 4) o0[m] = v; else o1[m - 4] = v;
    }
    float* ob = out + (((size_t)(b * 512 + o)) << 12) + s * 64 + half * 32 + 8 * rq;
    *(f32x4*)ob = o0;
    *(f32x4*)(ob + 4) = o1;
  }
}

// ---------------- launcher ----------------
extern "C" void kernel_launch(void* const* d_in, const int* in_sizes, int n_in,
                              void* d_out, int out_size, void* d_ws, size_t ws_size,
                              hipStream_t stream) {
  const float* x     = (const float*)d_in[0];
  const float* w_lat = (const float*)d_in[1];
  const float* convw = (const float*)d_in[2];
  const float* convb = (const float*)d_in[3];
  const float* affw  = (const float*)d_in[4];
  const float* affb  = (const float*)d_in[5];
  const float* upf   = (const float*)d_in[6];
  const float* dnf   = (const float*)d_in[7];
  float* out = (float*)d_out;

  char* ws = (char*)d_ws;
  float* s         = (float*)(ws + 0);
  float* s2        = (float*)(ws + 16384);
  float* rowscale  = (float*)(ws + 32768);
  float* W2        = (float*)(ws + 34816);
  float* dbuf      = (float*)(ws + 1083392);
  unsigned short* wbf = (unsigned short*)(ws + 1099776);
  unsigned short* xhp = (unsigned short*)(ws + 5818368);
  float* ybuf      = (float*)(ws + 43862016);

  styles_kernel<<<16, 256, 0, stream>>>(w_lat, affw, affb, s);
  norm_kernel<<<1, 256, 0, stream>>>(s, s2);
  rowscale_kernel<<<512, 256, 0, stream>>>(convw, rowscale);
  wprep_kernel<<<512, 256, 0, stream>>>(convw, rowscale, wbf, W2);
  demod_kernel<<<16, 256, 0, stream>>>(s2, W2, dbuf);

  hipMemsetAsync(xhp, 0, (size_t)XHP_ROWS * 512 * 2, stream);
  xprep_kernel<<<512, 256, 0, stream>>>(x, s, xhp);

  dim3 cgrid(2, 289);
  conv_kernel<<<cgrid, 256, 73728, stream>>>(wbf, xhp, dbuf, convb, ybuf);

  updown_kernel<<<8192, 256, 0, stream>>>(ybuf, upf, dnf, out);
}

// Round 10
// 362.094 us; speedup vs baseline: 1.1365x; 1.1365x over previous
//
#include <hip/hip_runtime.h>
#include <stdint.h>

// ---------------- types / helpers ----------------
typedef short short8 __attribute__((ext_vector_type(8)));
typedef float f32x4 __attribute__((ext_vector_type(4)));

__device__ __forceinline__ unsigned short f2bf(float f) {
  union { float f; unsigned u; } v; v.f = f;
  unsigned u = v.u;
  u += 0x7fffu + ((u >> 16) & 1u);   // RNE
  return (unsigned short)(u >> 16);
}

__device__ __forceinline__ void gl16(const void* g, void* l) {
  __builtin_amdgcn_global_load_lds(
      (__attribute__((address_space(1))) void*)(uintptr_t)g,
      (__attribute__((address_space(3))) void*)l, 16, 0, 0);
}

// Problem constants
#define NSPAT 36992
#define PLANE 4624        // 68*68
#define XHP_ROWS 37152    // NSPAT + margin rows

// ---------------- kernel 1: styles ----------------
__global__ void styles_kernel(const float* __restrict__ w_lat, const float* __restrict__ affw,
                              const float* __restrict__ affb, float* __restrict__ s) {
  int g = blockIdx.x * 256 + threadIdx.x;   // 0..4095
  int b = g >> 9, i = g & 511;
  const float4* wl = (const float4*)(w_lat + b * 512);
  const float4* aw = (const float4*)(affw + (size_t)i * 512);
  float acc = 0.f;
#pragma unroll 4
  for (int j = 0; j < 128; ++j) {
    float4 a = wl[j], c = aw[j];
    acc += a.x * c.x + a.y * c.y + a.z * c.z + a.w * c.w;
  }
  s[g] = acc * 0.044194173824159216f + affb[i];
}

// ---------------- kernel 2: global normalize s ----------------
__global__ void norm_kernel(float* __restrict__ s, float* __restrict__ s2) {
  __shared__ float red[256];
  int t = threadIdx.x;
  float acc = 0.f;
  for (int e = t; e < 4096; e += 256) { float v = s[e]; acc += v * v; }
  red[t] = acc; __syncthreads();
  for (int st = 128; st > 0; st >>= 1) {
    if (t < st) red[t] += red[t + st];
    __syncthreads();
  }
  float alpha = rsqrtf(red[0] * (1.0f / 4096.0f));
  for (int e = t; e < 4096; e += 256) {
    float v = s[e] * alpha;
    s[e] = v; s2[e] = v * v;
  }
}

// ---------------- kernel 3: per-output-channel weight scale ----------------
__global__ void rowscale_kernel(const float* __restrict__ convw, float* __restrict__ rowscale) {
  int o = blockIdx.x, t = threadIdx.x;
  const float* wr = convw + (size_t)o * 4608;
  float acc = 0.f;
  for (int e = t; e < 4608; e += 256) { float v = wr[e]; acc += v * v; }
  __shared__ float red[256];
  red[t] = acc; __syncthreads();
  for (int st = 128; st > 0; st >>= 1) {
    if (t < st) red[t] += red[t + st];
    __syncthreads();
  }
  if (t == 0) rowscale[o] = rsqrtf(red[0] * (1.0f / 4608.0f));
}

// ---------------- kernel 4: bf16 weights (tap, o, i) + W2 ----------------
__global__ void wprep_kernel(const float* __restrict__ convw, const float* __restrict__ rowscale,
                             unsigned short* __restrict__ wbf, float* __restrict__ W2) {
  int o = blockIdx.x, t = threadIdx.x;
  float sc = rowscale[o];
  for (int i = t; i < 512; i += 256) {
    const float* wp = convw + ((size_t)o * 512 + i) * 9;
    float w9[9]; float ss = 0.f;
#pragma unroll
    for (int m = 0; m < 9; ++m) { float v = wp[m] * sc; w9[m] = v; ss += v * v; }
    W2[((size_t)o << 9) + i] = ss;
#pragma unroll
    for (int m = 0; m < 9; ++m)
      wbf[(((size_t)m * 512 + o) << 9) + i] = f2bf(w9[m]);
  }
}

// ---------------- kernel 5: demod ----------------
__global__ void demod_kernel(const float* __restrict__ s2, const float* __restrict__ W2,
                             float* __restrict__ dbuf) {
  int g = blockIdx.x * 256 + threadIdx.x;
  int b = g >> 9, o = g & 511;
  const float4* sp = (const float4*)(s2 + b * 512);
  const float4* wp = (const float4*)(W2 + (size_t)o * 512);
  float acc = 1e-8f;
#pragma unroll 4
  for (int j = 0; j < 128; ++j) {
    float4 a = sp[j], c = wp[j];
    acc += a.x * c.x + a.y * c.y + a.z * c.z + a.w * c.w;
  }
  dbuf[g] = rsqrtf(acc);
}

// ---------------- kernel 6: x-hat NHWC padded bf16 ----------------
__global__ void xprep_kernel(const float* __restrict__ x, const float* __restrict__ s,
                             unsigned short* __restrict__ xhp) {
  int b = blockIdx.x >> 6, h = blockIdx.x & 63;
  int t = threadIdx.x;
  __shared__ float tile[64 * 65];
  __shared__ float sv[64];
  for (int it = 0; it < 8; ++it) {
    int i0 = it * 64;
    {
      int ii = t >> 2, wseg = (t & 3) * 16;
      const float4* src = (const float4*)(x + (((size_t)(b * 512 + i0 + ii) * 64 + h) << 6) + wseg);
      float4 v0 = src[0], v1 = src[1], v2 = src[2], v3 = src[3];
      float* dst = tile + ii * 65 + wseg;
      dst[0]=v0.x; dst[1]=v0.y; dst[2]=v0.z; dst[3]=v0.w;
      dst[4]=v1.x; dst[5]=v1.y; dst[6]=v1.z; dst[7]=v1.w;
      dst[8]=v2.x; dst[9]=v2.y; dst[10]=v2.z; dst[11]=v2.w;
      dst[12]=v3.x; dst[13]=v3.y; dst[14]=v3.z; dst[15]=v3.w;
    }
    if (t < 64) sv[t] = s[b * 512 + i0 + t];
    __syncthreads();
    {
      int w = t >> 2, ic = (t & 3) * 16;
      alignas(16) unsigned short tmp[16];
#pragma unroll
      for (int k = 0; k < 16; ++k)
        tmp[k] = f2bf(tile[(ic + k) * 65 + w] * sv[ic + k]);
      unsigned short* dst = xhp + ((size_t)b * PLANE + (h + 2) * 68 + (w + 2)) * 512 + i0 + ic;
      *(short8*)dst = *(const short8*)tmp;
      *(short8*)(dst + 8) = *(const short8*)(tmp + 8);
    }
    __syncthreads();
  }
}

// ---------------- kernel 7: implicit-GEMM conv, 128x128 tile, BK=64, 2-buf ring ----------------
// Per KT=64: ONE vmcnt(0) + ONE barrier (half R8's sync rate), prefetch distance = 1 full
// KT (~1240 cy > 900 cy HBM). Race-free: stage at iter k targets buf((k+1)&1), last read at
// iter k-2; the iter-k barrier separates it from iter k-1's reads. sigma LDS swizzle (proven
// 0 conflicts) and R8's grid/XCD mapping unchanged.
__global__ __launch_bounds__(256, 2) void conv_kernel(const unsigned short* __restrict__ wbf,
                                                      const unsigned short* __restrict__ xhp,
                                                      const float* __restrict__ dbuf,
                                                      const float* __restrict__ convb,
                                                      float* __restrict__ ybuf) {
  extern __shared__ unsigned short lds[];  // 2 bufs x (A 8192 + B 8192) shorts = 64 KB
  const int t = threadIdx.x;
  const int lane = t & 63, wid = t >> 6;

  // n-major order + bijective XCD chunking: orig = ntile*4 + otile (identical to R8)
  int orig = blockIdx.y * 4 + blockIdx.x;
  int xcd = orig & 7, idx = orig >> 3;
  int wg = (xcd < 4) ? (xcd * 145 + idx) : (580 + (xcd - 4) * 144 + idx);
  const int n0 = (wg >> 2) * 128, o0 = (wg & 3) * 128;
  const int wm = wid >> 1, wn = wid & 1;

  // staging: lane l stages global quarter q=(l&3)^((l>>3)&3) of row (base + wid*16 + (l>>2))
  const unsigned kcq = (((unsigned)(lane & 3)) ^ ((unsigned)(lane >> 3) & 3u)) * 8u;
  const unsigned aSrc = (unsigned)(o0 + wid * 16 + (lane >> 2)) * 512 + kcq;  // +c*32768, +kk*32
  const unsigned bSrc = (unsigned)(n0 + wid * 16 + (lane >> 2)) * 512 + kcq;

  // frag read: row r=lane&15, phys quarter = (lane>>4) ^ ((r>>1)&3)
  const unsigned xq = ((unsigned)(lane >> 4)) ^ (((unsigned)(lane & 15) >> 1) & 3u);
  const unsigned aRd = (unsigned)(wm * 64 + (lane & 15)) * 32 + xq * 8;   // + kk*4096 + mi*512
  const unsigned bRd = (unsigned)(wn * 64 + (lane & 15)) * 32 + xq * 8;   // + 8192 + kk*4096 + ni*512

  f32x4 acc[4][4] = {};

  // LDS per buf (shorts): A [kk][128 rows][32] at 0 ; B same at +8192 ; buf stride 16384
#define STAGE(kt, bufb) do {                                            \
    const unsigned kti = (unsigned)(kt);                                \
    const unsigned tap = kti >> 3, k0e = (kti & 7u) * 64u;              \
    const unsigned aB = tap * 262144u + k0e;                            \
    const unsigned bB = ((tap / 3u) * 68u + (tap % 3u)) * 512u + k0e;   \
    unsigned short* lb = lds + (bufb) * 16384 + wid * 512;              \
    gl16(wbf + aB + aSrc,              lb);                             \
    gl16(wbf + aB + aSrc + 32768,      lb + 2048);                      \
    gl16(wbf + aB + 32 + aSrc,         lb + 4096);                      \
    gl16(wbf + aB + 32 + aSrc + 32768, lb + 6144);                      \
    gl16(xhp + bB + bSrc,              lb + 8192);                      \
    gl16(xhp + bB + bSrc + 32768,      lb + 10240);                     \
    gl16(xhp + bB + 32 + bSrc,         lb + 12288);                     \
    gl16(xhp + bB + 32 + bSrc + 32768, lb + 14336);                     \
  } while (0)

#define COMPUTE_KK(bufb, kk) do {                                       \
    const unsigned short* aF = lds + (bufb) * 16384 + (kk) * 4096 + aRd;        \
    const unsigned short* bF = lds + (bufb) * 16384 + 8192 + (kk) * 4096 + bRd; \
    short8 a0 = *(const short8*)(aF + 0);                               \
    short8 a1 = *(const short8*)(aF + 512);                             \
    short8 a2 = *(const short8*)(aF + 1024);                            \
    short8 a3 = *(const short8*)(aF + 1536);                            \
    short8 b0 = *(const short8*)(bF + 0);                               \
    short8 b1 = *(const short8*)(bF + 512);                             \
    short8 b2 = *(const short8*)(bF + 1024);                            \
    short8 b3 = *(const short8*)(bF + 1536);                            \
    __builtin_amdgcn_s_setprio(1);                                      \
    acc[0][0] = __builtin_amdgcn_mfma_f32_16x16x32_bf16(a0, b0, acc[0][0], 0, 0, 0); \
    acc[0][1] = __builtin_amdgcn_mfma_f32_16x16x32_bf16(a0, b1, acc[0][1], 0, 0, 0); \
    acc[0][2] = __builtin_amdgcn_mfma_f32_16x16x32_bf16(a0, b2, acc[0][2], 0, 0, 0); \
    acc[0][3] = __builtin_amdgcn_mfma_f32_16x16x32_bf16(a0, b3, acc[0][3], 0, 0, 0); \
    acc[1][0] = __builtin_amdgcn_mfma_f32_16x16x32_bf16(a1, b0, acc[1][0], 0, 0, 0); \
    acc[1][1] = __builtin_amdgcn_mfma_f32_16x16x32_bf16(a1, b1, acc[1][1], 0, 0, 0); \
    acc[1][2] = __builtin_amdgcn_mfma_f32_16x16x32_bf16(a1, b2, acc[1][2], 0, 0, 0); \
    acc[1][3] = __builtin_amdgcn_mfma_f32_16x16x32_bf16(a1, b3, acc[1][3], 0, 0, 0); \
    acc[2][0] = __builtin_amdgcn_mfma_f32_16x16x32_bf16(a2, b0, acc[2][0], 0, 0, 0); \
    acc[2][1] = __builtin_amdgcn_mfma_f32_16x16x32_bf16(a2, b1, acc[2][1], 0, 0, 0); \
    acc[2][2] = __builtin_amdgcn_mfma_f32_16x16x32_bf16(a2, b2, acc[2][2], 0, 0, 0); \
    acc[2][3] = __builtin_amdgcn_mfma_f32_16x16x32_bf16(a2, b3, acc[2][3], 0, 0, 0); \
    acc[3][0] = __builtin_amdgcn_mfma_f32_16x16x32_bf16(a3, b0, acc[3][0], 0, 0, 0); \
    acc[3][1] = __builtin_amdgcn_mfma_f32_16x16x32_bf16(a3, b1, acc[3][1], 0, 0, 0); \
    acc[3][2] = __builtin_amdgcn_mfma_f32_16x16x32_bf16(a3, b2, acc[3][2], 0, 0, 0); \
    acc[3][3] = __builtin_amdgcn_mfma_f32_16x16x32_bf16(a3, b3, acc[3][3], 0, 0, 0); \
    __builtin_amdgcn_s_setprio(0);                                      \
  } while (0)

  STAGE(0, 0);

  for (int k = 0; k < 72; ++k) {
    asm volatile("s_waitcnt vmcnt(0)" ::: "memory");  // buf(k&1) fully landed (per wave)
    __builtin_amdgcn_s_barrier();                     // broadcast: all waves' stages landed;
    asm volatile("" ::: "memory");                    // also fences prev iter's reads vs stage below
    if (k < 71) STAGE(k + 1, (k + 1) & 1);
    __builtin_amdgcn_sched_barrier(0);                // keep gl16 issue ahead of the MFMA cluster
    COMPUTE_KK(k & 1, 0);
    COMPUTE_KK(k & 1, 1);
    asm volatile("" ::: "memory");
  }
#undef STAGE
#undef COMPUTE_KK

  // epilogue
  const int col = lane & 15;
  const int rbase = (lane >> 4) * 4;
#pragma unroll
  for (int ni = 0; ni < 4; ++ni) {
    const unsigned n = (unsigned)(n0 + wn * 64 + ni * 16 + col);
    const unsigned b = n / 4624u;
    const float* dr = dbuf + b * 512;
#pragma unroll
    for (int mi = 0; mi < 4; ++mi) {
      const int ob = o0 + wm * 64 + mi * 16 + rbase;
#pragma unroll
      for (int j = 0; j < 4; ++j) {
        const int o = ob + j;
        float v = acc[mi][ni][j] * dr[o] + convb[o];
        v = fminf(fmaxf(v, -256.f), 256.f);
        ybuf[(size_t)o * NSPAT + n] = v;
      }
    }
  }
}

// ---------------- kernel 8: fused up2 + lrelu + down2, z kept in registers ----------------
// (unchanged from R8 — proven)
__global__ __launch_bounds__(256, 4) void updown_kernel(const float* __restrict__ ybuf,
                                                        const float* __restrict__ upf,
                                                        const float* __restrict__ dnf,
                                                        float* __restrict__ out) {
  __shared__ float sm[9880];
  float* uhB = sm;            // [66][76]
  float* uB  = sm + 5016;     // [66][44]
  float* dvT = sm + 5016;     // [64][76] overlay (uB dead after P2)

  const int blk = blockIdx.x;
  const int half = blk & 1, ch = blk >> 1;
  const int o = ch & 511, b = ch >> 9;
  const float* ybase = ybuf + (size_t)o * NSPAT + b * PLANE;
  const int t = threadIdx.x;
  const int uc0 = half * 32 - 4;   // u window global col start (width 44)

  float f2[12], g[12];
#pragma unroll
  for (int m = 0; m < 12; ++m) { f2[m] = upf[11 - m] * 2.0f; g[m] = dnf[11 - m]; }

  // P1: load u window [66][44] via f32x4, zero-masked outside valid cols [0,66)
  for (int u = t; u < 726; u += 256) {
    int p = u / 11, q = u - p * 11;
    int gc = uc0 + 4 * q;
    f32x4 v = {0.f, 0.f, 0.f, 0.f};
    if (gc >= 0 && gc < 66) {
      v = *(const f32x4*)(ybase + p * 68 + gc);
#pragma unroll
      for (int j = 0; j < 4; ++j)
        if (gc + j >= 66) v[j] = 0.f;
    }
    *(f32x4*)(uB + p * 44 + 4 * q) = v;
  }
  __syncthreads();

  // P2: horizontal upsample. units (p<66, cq<19): uh local cols 4cq..4cq+3
  for (int u = t; u < 1254; u += 256) {
    int p = u / 19, cq = u - p * 19;
    const float* ur = uB + p * 44 + 2 * cq;
    float R0 = ur[0], R1 = ur[1], R2 = ur[2], R3 = ur[3], R4 = ur[4], R5 = ur[5], R6 = ur[6];
    f32x4 o4;
    o4[0] = f2[1]*R0 + f2[3]*R1 + f2[5]*R2 + f2[7]*R3 + f2[9]*R4 + f2[11]*R5;
    o4[1] = f2[0]*R0 + f2[2]*R1 + f2[4]*R2 + f2[6]*R3 + f2[8]*R4 + f2[10]*R5;
    o4[2] = f2[1]*R1 + f2[3]*R2 + f2[5]*R3 + f2[7]*R4 + f2[9]*R5 + f2[11]*R6;
    o4[3] = f2[0]*R1 + f2[2]*R2 + f2[4]*R3 + f2[6]*R4 + f2[8]*R5 + f2[10]*R6;
    *(f32x4*)(uhB + p * 76 + 4 * cq) = o4;
  }
  __syncthreads();

  // P3': fused vertical up + lrelu + vertical down, per column, z in registers.
  if (t < 225) {
    const int cl = t % 75, sg = t / 75;
    const int s0 = sg * 22;
    const int ttg0 = 2 * s0;
    float R[32];
#pragma unroll
    for (int k = 0; k < 32; ++k) {
      int j = s0 - 4 + k;
      R[k] = (j >= 0 && j < 66) ? uhB[j * 76 + cl] : 0.f;
    }
    float dv[22];
#pragma unroll
    for (int m = 0; m < 22; ++m) dv[m] = 0.f;
#pragma unroll
    for (int k = 0; k < 54; ++k) {
      const int kb = k >> 1;
      float z;
      if (k & 1)
        z = f2[0]*R[kb] + f2[2]*R[kb+1] + f2[4]*R[kb+2] + f2[6]*R[kb+3] + f2[8]*R[kb+4] + f2[10]*R[kb+5];
      else
        z = f2[1]*R[kb] + f2[3]*R[kb+1] + f2[5]*R[kb+2] + f2[7]*R[kb+3] + f2[9]*R[kb+4] + f2[11]*R[kb+5];
      z = (z > 0.f ? z : 0.2f * z) * 1.4142135623730951f;
      z = fminf(fmaxf(z, -256.f), 256.f);
      if (ttg0 + k >= 138) z = 0.f;
      const int mlo = (k < 11) ? 0 : ((k - 10) >> 1);
      const int mhi = ((k >> 1) < 21) ? (k >> 1) : 21;
#pragma unroll
      for (int m = mlo; m <= mhi; ++m)
        dv[m] += g[k - 2 * m] * z;
    }
#pragma unroll
    for (int m = 0; m < 22; ++m) {
      const int s = s0 + m;
      if (s < 64) dvT[s * 76 + cl] = dv[m];
    }
  }
  __syncthreads();

  // P4': horizontal downsample + store. units (s<64, rq<4), exactly 256
  {
    const int s = t >> 2, rq = t & 3;
    const float* dr = dvT + s * 76 + 16 * rq;
    f32x4 dd[7];
#pragma unroll
    for (int i = 0; i < 7; ++i) dd[i] = *(const f32x4*)(dr + 4 * i);
    float D[28];
#pragma unroll
    for (int i = 0; i < 7; ++i) {
      D[4*i+0] = dd[i][0]; D[4*i+1] = dd[i][1]; D[4*i+2] = dd[i][2]; D[4*i+3] = dd[i][3];
    }
    f32x4 o0, o1;
#pragma unroll
    for (int m = 0; m < 8; ++m) {
      float v = g[0]*D[2*m] + g[1]*D[2*m+1] + g[2]*D[2*m+2] + g[3]*D[2*m+3]
              + g[4]*D[2*m+4] + g[5]*D[2*m+5] + g[6]*D[2*m+6] + g[7]*D[2*m+7]
              + g[8]*D[2*m+8] + g[9]*D[2*m+9] + g[10]*D[2*m+10] + g[11]*D[2*m+11];
      if (m < 4) o0[m] = v; else o1[m - 4] = v;
    }
    float* ob = out + (((size_t)(b * 512 + o)) << 12) + s * 64 + half * 32 + 8 * rq;
    *(f32x4*)ob = o0;
    *(f32x4*)(ob + 4) = o1;
  }
}

// ---------------- launcher ----------------
extern "C" void kernel_launch(void* const* d_in, const int* in_sizes, int n_in,
                              void* d_out, int out_size, void* d_ws, size_t ws_size,
                              hipStream_t stream) {
  const float* x     = (const float*)d_in[0];
  const float* w_lat = (const float*)d_in[1];
  const float* convw = (const float*)d_in[2];
  const float* convb = (const float*)d_in[3];
  const float* affw  = (const float*)d_in[4];
  const float* affb  = (const float*)d_in[5];
  const float* upf   = (const float*)d_in[6];
  const float* dnf   = (const float*)d_in[7];
  float* out = (float*)d_out;

  char* ws = (char*)d_ws;
  float* s         = (float*)(ws + 0);
  float* s2        = (float*)(ws + 16384);
  float* rowscale  = (float*)(ws + 32768);
  float* W2        = (float*)(ws + 34816);
  float* dbuf      = (float*)(ws + 1083392);
  unsigned short* wbf = (unsigned short*)(ws + 1099776);
  unsigned short* xhp = (unsigned short*)(ws + 5818368);
  float* ybuf      = (float*)(ws + 43862016);

  styles_kernel<<<16, 256, 0, stream>>>(w_lat, affw, affb, s);
  norm_kernel<<<1, 256, 0, stream>>>(s, s2);
  rowscale_kernel<<<512, 256, 0, stream>>>(convw, rowscale);
  wprep_kernel<<<512, 256, 0, stream>>>(convw, rowscale, wbf, W2);
  demod_kernel<<<16, 256, 0, stream>>>(s2, W2, dbuf);

  hipMemsetAsync(xhp, 0, (size_t)XHP_ROWS * 512 * 2, stream);
  xprep_kernel<<<512, 256, 0, stream>>>(x, s, xhp);

  dim3 cgrid(4, 289);
  conv_kernel<<<cgrid, 256, 65536, stream>>>(wbf, xhp, dbuf, convb, ybuf);

  updown_kernel<<<8192, 256, 0, stream>>>(ybuf, upf, dnf, out);
}